// Round 1
// baseline (246.277 us; speedup 1.0000x reference)
//
#include <hip/hip_runtime.h>

// MHA forward, MI355X gfx950. bf16 MFMA pipeline, fp32 accumulate.
// Stages: cvt(fp32->bf16) -> fused QKV gemm_bt (epilogue: Q*scale, K, V^T)
//         -> flash attention (causal, online softmax) -> out-proj gemm_bt.

#define DM   768
#define SEQ  2048
#define NB   2
#define NH   12
#define DK   64
#define MROWS (NB*SEQ)                       // 4096
#define QSCALE 0.18033688011112042f          // (1/sqrt(64)) * log2(e): softmax in exp2 domain

typedef unsigned short u16;
typedef __bf16 bf16x8 __attribute__((ext_vector_type(8)));
typedef float  f32x4  __attribute__((ext_vector_type(4)));
typedef unsigned int u32x4 __attribute__((ext_vector_type(4)));

__device__ __forceinline__ u16 f2bf(float f) {      // RNE f32 -> bf16
  unsigned u = __builtin_bit_cast(unsigned, f);
  u += 0x7fffu + ((u >> 16) & 1u);
  return (u16)(u >> 16);
}

__device__ __forceinline__ bf16x8 ldbf8(const u16* p) {   // 16B aligned load
  return __builtin_bit_cast(bf16x8, *(const u32x4*)p);
}

__device__ __forceinline__ void gl_lds16(const void* g, void* l) {
  __builtin_amdgcn_global_load_lds((__attribute__((address_space(1))) void*)g,
                                   (__attribute__((address_space(3))) void*)l,
                                   16, 0, 0);
}

// ---------------- fp32 -> bf16 convert (x4 vectorized) ----------------
__global__ void cvt_bf16(const float* __restrict__ s, u16* __restrict__ d, int n4) {
  int i = blockIdx.x * blockDim.x + threadIdx.x;
  if (i < n4) {
    const float4 v = ((const float4*)s)[i];
    ushort4 r;
    r.x = f2bf(v.x); r.y = f2bf(v.y); r.z = f2bf(v.z); r.w = f2bf(v.w);
    ((ushort4*)d)[i] = r;
  }
}

// ---------------- gemm_bt: C[m][n] = sum_k A[m][k]*B[n][k]  (m97 structure) ----
// EPI 0: fused QKV (A=xb, B0/1/2 = wq/wk/wv), scatter Q(scaled)/K -> [b,h,s,d], V -> [b,h,d,s]
// EPI 1: out-proj (A=attb, B0=wo), f32 out + bias
template <int EPI>
__global__ __launch_bounds__(256) void gemm_bt(
    const u16* __restrict__ A,
    const u16* __restrict__ B0, const u16* __restrict__ B1, const u16* __restrict__ B2,
    const float* __restrict__ bias0, const float* __restrict__ bias1, const float* __restrict__ bias2,
    u16* __restrict__ q_out, u16* __restrict__ k_out, u16* __restrict__ vt_out,
    float* __restrict__ f_out)
{
  __shared__ u16 At[128*32];
  __shared__ u16 Bt[128*32];
  const int tid = threadIdx.x;
  const int w = tid >> 6, lane = tid & 63;
  const int lg = lane >> 4, ll = lane & 15;
  const int bn = blockIdx.x, bm = blockIdx.y;
  const int row0 = bm * 128;

  const u16* Bm; const float* bias; int col0; int mat = 0;
  if (EPI == 0) {
    mat  = bn / 6;                               // 0=Q 1=K 2=V (768/128=6 blocks each)
    Bm   = (mat == 0) ? B0 : (mat == 1) ? B1 : B2;
    bias = (mat == 0) ? bias0 : (mat == 1) ? bias1 : bias2;
    col0 = (bn % 6) * 128;
  } else {
    Bm = B0; bias = bias0; col0 = bn * 128;
  }
  const int wr = w >> 1, wc = w & 1;             // wave -> 64x64 quadrant

  f32x4 acc[4][4] = {};
  const int c0 = w, c1 = w + 4;                  // two 1KB chunks per wave per tile
  const int ofs0 = c0*1024 + lane*16;            // byte offset in 128x32 bf16 tile
  const int ofs1 = c1*1024 + lane*16;

  for (int k0 = 0; k0 < DM; k0 += 32) {
    __syncthreads();   // previous tile's reads done before overwrite
    gl_lds16((const char*)A  + ((size_t)(row0 + (ofs0>>6))*DM + k0)*2 + (ofs0&63), (char*)At + c0*1024);
    gl_lds16((const char*)A  + ((size_t)(row0 + (ofs1>>6))*DM + k0)*2 + (ofs1&63), (char*)At + c1*1024);
    gl_lds16((const char*)Bm + ((size_t)(col0 + (ofs0>>6))*DM + k0)*2 + (ofs0&63), (char*)Bt + c0*1024);
    gl_lds16((const char*)Bm + ((size_t)(col0 + (ofs1>>6))*DM + k0)*2 + (ofs1&63), (char*)Bt + c1*1024);
    __syncthreads();   // drains vmcnt (compiler-inserted) -> staging complete

    bf16x8 fa[4], fb[4];
#pragma unroll
    for (int m = 0; m < 4; ++m)
      fa[m] = ldbf8(&At[(wr*64 + m*16 + ll)*32 + lg*8]);
#pragma unroll
    for (int n = 0; n < 4; ++n)
      fb[n] = ldbf8(&Bt[(wc*64 + n*16 + ll)*32 + lg*8]);
#pragma unroll
    for (int m = 0; m < 4; ++m)
#pragma unroll
      for (int n = 0; n < 4; ++n)
        acc[m][n] = __builtin_amdgcn_mfma_f32_16x16x32_bf16(fa[m], fb[n], acc[m][n], 0, 0, 0);
  }

  // epilogue: C/D layout col=lane&15, row=(lane>>4)*4+j (m89-verified)
#pragma unroll
  for (int m = 0; m < 4; ++m) {
#pragma unroll
    for (int n = 0; n < 4; ++n) {
      const int gn  = col0 + wc*64 + n*16 + ll;
      const float bv = bias[gn];
      const int gm0 = row0 + wr*64 + m*16 + lg*4;
#pragma unroll
      for (int j = 0; j < 4; ++j) {
        const float v = acc[m][n][j] + bv;
        const int gm = gm0 + j;
        if (EPI == 0) {
          const int b = gm >> 11, s = gm & 2047;
          const int h = gn >> 6,  d = gn & 63;
          const size_t bh = (size_t)(b*NH + h);
          if (mat == 0)      q_out[(bh*SEQ + s)*DK + d] = f2bf(v * QSCALE);
          else if (mat == 1) k_out[(bh*SEQ + s)*DK + d] = f2bf(v);
          else               vt_out[(bh*DK + d)*SEQ + s] = f2bf(v);
        } else {
          f_out[(size_t)gm*DM + gn] = v;
        }
      }
    }
  }
}

// ---------------- flash attention, causal ----------------
// grid (32, 24): x -> q-tile (reversed: heavy first), y -> (b*NH+h)
// block 256 = 4 waves; wave w owns 16 q-rows; KV tiles of 64.
__global__ __launch_bounds__(256) void attn_fwd(
    const u16* __restrict__ qb, const u16* __restrict__ kb,
    const u16* __restrict__ vtb, u16* __restrict__ attb)
{
  __shared__ u16 Pl[4][16][72];                  // per-wave P tile, pad 64->72 (bank spread)
  const int bh = blockIdx.y;
  const int qt = (int)gridDim.x - 1 - (int)blockIdx.x;
  const int tid = threadIdx.x;
  const int w = tid >> 6, lane = tid & 63;
  const int lg = lane >> 4, ll = lane & 15;
  const u16* qp = qb  + (size_t)bh * SEQ * DK;
  const u16* kp = kb  + (size_t)bh * SEQ * DK;
  const u16* vp = vtb + (size_t)bh * DK * SEQ;   // V^T: [d][s]
  const int q0 = qt * 64 + w * 16;

  bf16x8 qf[2];
#pragma unroll
  for (int h2 = 0; h2 < 2; ++h2)
    qf[h2] = ldbf8(&qp[(size_t)(q0 + ll)*DK + h2*32 + lg*8]);

  f32x4 o[4] = {};
  float mrun[4], lrun[4];
#pragma unroll
  for (int j = 0; j < 4; ++j) { mrun[j] = -1e30f; lrun[j] = 0.f; }

  for (int t = 0; t <= qt; ++t) {
    const int kv0 = t * 64;
    f32x4 s[4] = {};
#pragma unroll
    for (int n = 0; n < 4; ++n) {
      const u16* kr = &kp[(size_t)(kv0 + n*16 + ll)*DK + lg*8];
      s[n] = __builtin_amdgcn_mfma_f32_16x16x32_bf16(qf[0], ldbf8(kr),      s[n], 0,0,0);
      s[n] = __builtin_amdgcn_mfma_f32_16x16x32_bf16(qf[1], ldbf8(kr + 32), s[n], 0,0,0);
    }
    if (t == qt) {                                // diagonal tile: causal mask
#pragma unroll
      for (int n = 0; n < 4; ++n) {
        const int kg = kv0 + n*16 + ll;
#pragma unroll
        for (int j = 0; j < 4; ++j) {
          const int qg = q0 + lg*4 + j;
          if (kg > qg) s[n][j] = -1e30f;
        }
      }
    }
    // online softmax (exp2 domain; scale folded into Q)
    float mt[4];
#pragma unroll
    for (int j = 0; j < 4; ++j)
      mt[j] = fmaxf(fmaxf(s[0][j], s[1][j]), fmaxf(s[2][j], s[3][j]));
#pragma unroll
    for (int msk = 1; msk < 16; msk <<= 1)
#pragma unroll
      for (int j = 0; j < 4; ++j)
        mt[j] = fmaxf(mt[j], __shfl_xor(mt[j], msk));
    float sc[4];
#pragma unroll
    for (int j = 0; j < 4; ++j) {
      const float mn = fmaxf(mrun[j], mt[j]);
      sc[j] = exp2f(mrun[j] - mn);
      mrun[j] = mn;
    }
    float p[4][4], ps[4];
#pragma unroll
    for (int n = 0; n < 4; ++n)
#pragma unroll
      for (int j = 0; j < 4; ++j)
        p[n][j] = exp2f(s[n][j] - mrun[j]);
#pragma unroll
    for (int j = 0; j < 4; ++j)
      ps[j] = (p[0][j] + p[1][j]) + (p[2][j] + p[3][j]);
#pragma unroll
    for (int msk = 1; msk < 16; msk <<= 1)
#pragma unroll
      for (int j = 0; j < 4; ++j)
        ps[j] += __shfl_xor(ps[j], msk);
#pragma unroll
    for (int j = 0; j < 4; ++j)
      lrun[j] = lrun[j] * sc[j] + ps[j];
#pragma unroll
    for (int n = 0; n < 4; ++n)
#pragma unroll
      for (int j = 0; j < 4; ++j)
        o[n][j] *= sc[j];
    // P (acc layout) -> LDS -> A-operand layout for PV
#pragma unroll
    for (int n = 0; n < 4; ++n)
#pragma unroll
      for (int j = 0; j < 4; ++j)
        Pl[w][lg*4 + j][n*16 + ll] = f2bf(p[n][j]);
    const bf16x8 pa0 = ldbf8(&Pl[w][ll][lg*8]);        // same-wave LDS RAW: in-order, no barrier
    const bf16x8 pa1 = ldbf8(&Pl[w][ll][32 + lg*8]);
#pragma unroll
    for (int n = 0; n < 4; ++n) {
      const u16* vr = &vp[(size_t)(n*16 + ll)*SEQ + kv0 + lg*8];
      o[n] = __builtin_amdgcn_mfma_f32_16x16x32_bf16(pa0, ldbf8(vr),      o[n], 0,0,0);
      o[n] = __builtin_amdgcn_mfma_f32_16x16x32_bf16(pa1, ldbf8(vr + 32), o[n], 0,0,0);
    }
  }
  // normalize + store to att buffer [b*S+s][h*64+d] bf16
  const int b = bh / NH, hh = bh % NH;
#pragma unroll
  for (int n = 0; n < 4; ++n) {
#pragma unroll
    for (int j = 0; j < 4; ++j) {
      const float v = o[n][j] / lrun[j];
      const int row = q0 + lg*4 + j;
      const int col = hh*64 + n*16 + ll;
      attb[(size_t)(b*SEQ + row)*DM + col] = f2bf(v);
    }
  }
}

// ---------------- launch ----------------
extern "C" void kernel_launch(void* const* d_in, const int* in_sizes, int n_in,
                              void* d_out, int out_size, void* d_ws, size_t ws_size,
                              hipStream_t stream) {
  const float* x  = (const float*)d_in[0];
  const float* wq = (const float*)d_in[1];
  const float* bq = (const float*)d_in[2];
  const float* wk = (const float*)d_in[3];
  const float* bk = (const float*)d_in[4];
  const float* wv = (const float*)d_in[5];
  const float* bv = (const float*)d_in[6];
  const float* wo = (const float*)d_in[7];
  const float* bo = (const float*)d_in[8];
  float* out = (float*)d_out;

  char* ws = (char*)d_ws;
  u16* xb   = (u16*)(ws);               // [4096][768]        6291456 B
  u16* wqb  = (u16*)(ws + 6291456);     // [768][768]         1179648 B
  u16* wkb  = (u16*)(ws + 7471104);
  u16* wvb  = (u16*)(ws + 8650752);
  u16* wob  = (u16*)(ws + 9830400);
  u16* qb   = (u16*)(ws + 11010048);    // [24][2048][64] scaled
  u16* kb   = (u16*)(ws + 17301504);    // [24][2048][64]
  u16* vtb  = (u16*)(ws + 23592960);    // [24][64][2048]
  u16* attb = (u16*)(ws + 29884416);    // [4096][768]

  const int nx4 = MROWS*DM/4;           // 786432
  const int nw4 = DM*DM/4;              // 147456
  cvt_bf16<<<(nx4+255)/256, 256, 0, stream>>>(x,  xb,  nx4);
  cvt_bf16<<<(nw4+255)/256, 256, 0, stream>>>(wq, wqb, nw4);
  cvt_bf16<<<(nw4+255)/256, 256, 0, stream>>>(wk, wkb, nw4);
  cvt_bf16<<<(nw4+255)/256, 256, 0, stream>>>(wv, wvb, nw4);
  cvt_bf16<<<(nw4+255)/256, 256, 0, stream>>>(wo, wob, nw4);

  gemm_bt<0><<<dim3(18, 32), 256, 0, stream>>>(xb, wqb, wkb, wvb, bq, bk, bv,
                                               qb, kb, vtb, nullptr);
  attn_fwd<<<dim3(32, 24), 256, 0, stream>>>(qb, kb, vtb, attb);
  gemm_bt<1><<<dim3(6, 32), 256, 0, stream>>>(attb, wob, nullptr, nullptr, bo, nullptr, nullptr,
                                              nullptr, nullptr, nullptr, out);
}

// Round 2
// 150.517 us; speedup vs baseline: 1.6362x; 1.6362x over previous
//
#include <hip/hip_runtime.h>

// MHA forward, MI355X gfx950. bf16 MFMA pipeline, fp32 accumulate.
// Stages: cvt(fp32->bf16) -> fused QKV gemm_bt (epilogue: Q*scale, K, V^T)
//         -> flash attention (swapped QK^T, LDS-staged dbuf K/V) -> out-proj gemm_bt.

#define DM   768
#define SEQ  2048
#define NB   2
#define NH   12
#define DK   64
#define MROWS (NB*SEQ)                       // 4096
#define QSCALE 0.18033688011112042f          // (1/sqrt(64)) * log2(e): softmax in exp2 domain

typedef unsigned short u16;
typedef __bf16 bf16x8 __attribute__((ext_vector_type(8)));
typedef float  f32x4  __attribute__((ext_vector_type(4)));
typedef unsigned int u32x4 __attribute__((ext_vector_type(4)));

__device__ __forceinline__ u16 f2bf(float f) {      // RNE f32 -> bf16
  unsigned u = __builtin_bit_cast(unsigned, f);
  u += 0x7fffu + ((u >> 16) & 1u);
  return (u16)(u >> 16);
}

__device__ __forceinline__ bf16x8 ldbf8(const u16* p) {   // 16B aligned load
  return __builtin_bit_cast(bf16x8, *(const u32x4*)p);
}

__device__ __forceinline__ void gl_lds16(const void* g, void* l) {
  __builtin_amdgcn_global_load_lds((__attribute__((address_space(1))) void*)g,
                                   (__attribute__((address_space(3))) void*)l,
                                   16, 0, 0);
}

// ---------------- fp32 -> bf16 convert (x4 vectorized) ----------------
__global__ void cvt_bf16(const float* __restrict__ s, u16* __restrict__ d, int n4) {
  int i = blockIdx.x * blockDim.x + threadIdx.x;
  if (i < n4) {
    const float4 v = ((const float4*)s)[i];
    ushort4 r;
    r.x = f2bf(v.x); r.y = f2bf(v.y); r.z = f2bf(v.z); r.w = f2bf(v.w);
    ((ushort4*)d)[i] = r;
  }
}

// ---------------- gemm_bt: C[m][n] = sum_k A[m][k]*B[n][k]  (m97 structure) ----
template <int EPI>
__global__ __launch_bounds__(256) void gemm_bt(
    const u16* __restrict__ A,
    const u16* __restrict__ B0, const u16* __restrict__ B1, const u16* __restrict__ B2,
    const float* __restrict__ bias0, const float* __restrict__ bias1, const float* __restrict__ bias2,
    u16* __restrict__ q_out, u16* __restrict__ k_out, u16* __restrict__ vt_out,
    float* __restrict__ f_out)
{
  __shared__ u16 At[128*32];
  __shared__ u16 Bt[128*32];
  const int tid = threadIdx.x;
  const int w = tid >> 6, lane = tid & 63;
  const int lg = lane >> 4, ll = lane & 15;
  const int bn = blockIdx.x, bm = blockIdx.y;
  const int row0 = bm * 128;

  const u16* Bm; const float* bias; int col0; int mat = 0;
  if (EPI == 0) {
    mat  = bn / 6;                               // 0=Q 1=K 2=V
    Bm   = (mat == 0) ? B0 : (mat == 1) ? B1 : B2;
    bias = (mat == 0) ? bias0 : (mat == 1) ? bias1 : bias2;
    col0 = (bn % 6) * 128;
  } else {
    Bm = B0; bias = bias0; col0 = bn * 128;
  }
  const int wr = w >> 1, wc = w & 1;

  f32x4 acc[4][4] = {};
  const int c0 = w, c1 = w + 4;
  const int ofs0 = c0*1024 + lane*16;
  const int ofs1 = c1*1024 + lane*16;

  for (int k0 = 0; k0 < DM; k0 += 32) {
    __syncthreads();
    gl_lds16((const char*)A  + ((size_t)(row0 + (ofs0>>6))*DM + k0)*2 + (ofs0&63), (char*)At + c0*1024);
    gl_lds16((const char*)A  + ((size_t)(row0 + (ofs1>>6))*DM + k0)*2 + (ofs1&63), (char*)At + c1*1024);
    gl_lds16((const char*)Bm + ((size_t)(col0 + (ofs0>>6))*DM + k0)*2 + (ofs0&63), (char*)Bt + c0*1024);
    gl_lds16((const char*)Bm + ((size_t)(col0 + (ofs1>>6))*DM + k0)*2 + (ofs1&63), (char*)Bt + c1*1024);
    __syncthreads();

    bf16x8 fa[4], fb[4];
#pragma unroll
    for (int m = 0; m < 4; ++m)
      fa[m] = ldbf8(&At[(wr*64 + m*16 + ll)*32 + lg*8]);
#pragma unroll
    for (int n = 0; n < 4; ++n)
      fb[n] = ldbf8(&Bt[(wc*64 + n*16 + ll)*32 + lg*8]);
#pragma unroll
    for (int m = 0; m < 4; ++m)
#pragma unroll
      for (int n = 0; n < 4; ++n)
        acc[m][n] = __builtin_amdgcn_mfma_f32_16x16x32_bf16(fa[m], fb[n], acc[m][n], 0, 0, 0);
  }

#pragma unroll
  for (int m = 0; m < 4; ++m) {
#pragma unroll
    for (int n = 0; n < 4; ++n) {
      const int gn  = col0 + wc*64 + n*16 + ll;
      const float bv = bias[gn];
      const int gm0 = row0 + wr*64 + m*16 + lg*4;
#pragma unroll
      for (int j = 0; j < 4; ++j) {
        const float v = acc[m][n][j] + bv;
        const int gm = gm0 + j;
        if (EPI == 0) {
          const int b = gm >> 11, s = gm & 2047;
          const int h = gn >> 6,  d = gn & 63;
          const size_t bh = (size_t)(b*NH + h);
          if (mat == 0)      q_out[(bh*SEQ + s)*DK + d] = f2bf(v * QSCALE);
          else if (mat == 1) k_out[(bh*SEQ + s)*DK + d] = f2bf(v);
          else               vt_out[(bh*DK + d)*SEQ + s] = f2bf(v);
        } else {
          f_out[(size_t)gm*DM + gn] = v;
        }
      }
    }
  }
}

// ---------------- flash attention v2: swapped QK^T, LDS dbuf K/V ----------------
// grid (32, 24): x -> q-tile (reversed: heavy first), y -> (b*NH+h)
// block 256 = 4 waves; wave w owns 16 q-rows (q = q0+ll in MFMA N-dim); KV tiles of 64.
// S^T = mfma(K,Q): lane (ll,lg) holds S[q0+ll][k = kv0+kt*16+lg*4+j] -> row-reductions
// are 15 in-reg ops + 2 shuffles; m/l/scale are per-lane scalars.
// K/V tiles staged via global_load_lds w=16, XOR-swizzled (byte^=(row&7)<<4, source-side
// pre-swizzle per rule #21), double-buffered: stage(t+1) -> compute(t) -> one barrier.

__device__ __forceinline__ void stage_kv(const u16* kp, const u16* vp, int kv0,
                                         u16* Kb, u16* Vb, int w, int lane) {
  const char* kg = (const char*)kp + (size_t)kv0 * 128;   // K rows contiguous (128B/row)
  const char* vg = (const char*)vp + (size_t)kv0 * 2;     // V^T rows stride 4096B
#pragma unroll
  for (int r = 0; r < 2; ++r) {
    const int base = (w*2 + r) * 1024;          // wave-uniform LDS base; HW adds lane*16
    const int a = base + lane*16;               // this lane's LDS landing slot
    const int row = a >> 7;                     // 128B rows
    const int cs  = ((a >> 4) & 7) ^ (row & 7); // inverse-swizzled source chunk
    gl_lds16(kg + row*128 + cs*16, (char*)Kb + base);
    gl_lds16(vg + (size_t)row*4096 + cs*16, (char*)Vb + base);
  }
}

__device__ __forceinline__ bf16x8 ldtile(const u16* T, int row, int wo) {
  // swizzled read of 16B at logical (row, byte-offset wo) from a [64][64] bf16 tile
  return ldbf8((const u16*)((const char*)T + row*128 + (wo ^ ((row & 7) << 4))));
}

__global__ __launch_bounds__(256) void attn_fwd(
    const u16* __restrict__ qb, const u16* __restrict__ kb,
    const u16* __restrict__ vtb, u16* __restrict__ attb)
{
  __shared__ u16 Kt[2][64*64];                  // 8KB per buffer
  __shared__ u16 Vt[2][64*64];
  __shared__ u16 Pw[4][16*72];                  // per-wave P repack, pad 64->72
  const int bh = blockIdx.y;
  const int qt = (int)gridDim.x - 1 - (int)blockIdx.x;
  const int tid = threadIdx.x;
  const int w = tid >> 6, lane = tid & 63;
  const int lg = lane >> 4, ll = lane & 15;
  const u16* qp = qb  + (size_t)bh * SEQ * DK;
  const u16* kp = kb  + (size_t)bh * SEQ * DK;
  const u16* vp = vtb + (size_t)bh * DK * SEQ;
  const int q0 = qt * 64 + w * 16;

  // Q fragment (B-operand: lane (ll,lg) holds Q[q0+ll][lg*8..+7])
  const bf16x8 qf0 = ldbf8(&qp[(size_t)(q0 + ll)*DK + lg*8]);
  const bf16x8 qf1 = ldbf8(&qp[(size_t)(q0 + ll)*DK + 32 + lg*8]);

  f32x4 o[4] = {};                               // O^T frags: lane holds O[q0+ll][dt*16+lg*4+j]
  float mrun = -1e30f, lrun = 0.f;               // per-lane scalars (one q-row per lane)
  u16* Pl = &Pw[w][0];

  stage_kv(kp, vp, 0, Kt[0], Vt[0], w, lane);
  __syncthreads();

  for (int t = 0; t <= qt; ++t) {
    const int cur = t & 1;
    if (t < qt) stage_kv(kp, vp, (t+1)*64, Kt[cur^1], Vt[cur^1], w, lane);
    const u16* Kc = Kt[cur];
    const u16* Vc = Vt[cur];

    // S^T = K . Q^T over d=64
    f32x4 st[4] = {};
#pragma unroll
    for (int kt = 0; kt < 4; ++kt) {
      const int r = kt*16 + ll;
      st[kt] = __builtin_amdgcn_mfma_f32_16x16x32_bf16(ldtile(Kc, r, lg*16),      qf0, st[kt], 0,0,0);
      st[kt] = __builtin_amdgcn_mfma_f32_16x16x32_bf16(ldtile(Kc, r, 64 + lg*16), qf1, st[kt], 0,0,0);
    }
    if (t == qt) {                               // diagonal tile: causal mask
      const int kvb = t*64;
#pragma unroll
      for (int kt = 0; kt < 4; ++kt)
#pragma unroll
        for (int j = 0; j < 4; ++j)
          if (kvb + kt*16 + lg*4 + j > q0 + ll) st[kt][j] = -1e30f;
    }

    // online softmax: in-register row reduce + 2 shuffles
    float mt = -1e30f;
#pragma unroll
    for (int kt = 0; kt < 4; ++kt)
      mt = fmaxf(mt, fmaxf(fmaxf(st[kt][0], st[kt][1]), fmaxf(st[kt][2], st[kt][3])));
    mt = fmaxf(mt, __shfl_xor(mt, 16));
    mt = fmaxf(mt, __shfl_xor(mt, 32));
    const float mn = fmaxf(mrun, mt);
    const float sc = exp2f(mrun - mn);
    mrun = mn;

    float psum = 0.f;
    unsigned pd[8];
#pragma unroll
    for (int kt = 0; kt < 4; ++kt) {
      const float e0 = exp2f(st[kt][0] - mn);
      const float e1 = exp2f(st[kt][1] - mn);
      const float e2 = exp2f(st[kt][2] - mn);
      const float e3 = exp2f(st[kt][3] - mn);
      psum += (e0 + e1) + (e2 + e3);
      pd[kt*2]   = (unsigned)f2bf(e0) | ((unsigned)f2bf(e1) << 16);
      pd[kt*2+1] = (unsigned)f2bf(e2) | ((unsigned)f2bf(e3) << 16);
    }
    psum += __shfl_xor(psum, 16);
    psum += __shfl_xor(psum, 32);
    lrun = lrun * sc + psum;
#pragma unroll
    for (int dt = 0; dt < 4; ++dt)
#pragma unroll
      for (int j = 0; j < 4; ++j)
        o[dt][j] *= sc;

    // P repack (same-wave LDS round-trip; DS in-order within wave)
#pragma unroll
    for (int kt = 0; kt < 4; ++kt)
      *(uint2*)&Pl[ll*72 + kt*16 + lg*4] = make_uint2(pd[kt*2], pd[kt*2+1]);
    const bf16x8 pb0 = ldbf8(&Pl[ll*72 + lg*8]);       // P[q=ll][lg*8..+7]
    const bf16x8 pb1 = ldbf8(&Pl[ll*72 + 32 + lg*8]);

    // O^T += V^T . P^T
#pragma unroll
    for (int dt = 0; dt < 4; ++dt) {
      const int r = dt*16 + ll;
      o[dt] = __builtin_amdgcn_mfma_f32_16x16x32_bf16(ldtile(Vc, r, lg*16),      pb0, o[dt], 0,0,0);
      o[dt] = __builtin_amdgcn_mfma_f32_16x16x32_bf16(ldtile(Vc, r, 64 + lg*16), pb1, o[dt], 0,0,0);
    }
    __syncthreads();   // drains vmcnt (stage t+1 done) + all waves' LDS reads of buf[cur]
  }

  // store: lane owns q-row q0+ll, d contiguous in j
  const int b = bh / NH, hh = bh % NH;
  const float rl = 1.0f / lrun;
  u16* orow = &attb[(size_t)(b*SEQ + q0 + ll)*DM + hh*64];
#pragma unroll
  for (int dt = 0; dt < 4; ++dt) {
    ushort4 rr;
    rr.x = f2bf(o[dt][0] * rl);
    rr.y = f2bf(o[dt][1] * rl);
    rr.z = f2bf(o[dt][2] * rl);
    rr.w = f2bf(o[dt][3] * rl);
    *(ushort4*)&orow[dt*16 + lg*4] = rr;
  }
}

// ---------------- launch ----------------
extern "C" void kernel_launch(void* const* d_in, const int* in_sizes, int n_in,
                              void* d_out, int out_size, void* d_ws, size_t ws_size,
                              hipStream_t stream) {
  const float* x  = (const float*)d_in[0];
  const float* wq = (const float*)d_in[1];
  const float* bq = (const float*)d_in[2];
  const float* wk = (const float*)d_in[3];
  const float* bk = (const float*)d_in[4];
  const float* wv = (const float*)d_in[5];
  const float* bv = (const float*)d_in[6];
  const float* wo = (const float*)d_in[7];
  const float* bo = (const float*)d_in[8];
  float* out = (float*)d_out;

  char* ws = (char*)d_ws;
  u16* xb   = (u16*)(ws);               // [4096][768]
  u16* wqb  = (u16*)(ws + 6291456);     // [768][768]
  u16* wkb  = (u16*)(ws + 7471104);
  u16* wvb  = (u16*)(ws + 8650752);
  u16* wob  = (u16*)(ws + 9830400);
  u16* qb   = (u16*)(ws + 11010048);    // [24][2048][64] scaled
  u16* kb   = (u16*)(ws + 17301504);    // [24][2048][64]
  u16* vtb  = (u16*)(ws + 23592960);    // [24][64][2048]
  u16* attb = (u16*)(ws + 29884416);    // [4096][768]

  const int nx4 = MROWS*DM/4;
  const int nw4 = DM*DM/4;
  cvt_bf16<<<(nx4+255)/256, 256, 0, stream>>>(x,  xb,  nx4);
  cvt_bf16<<<(nw4+255)/256, 256, 0, stream>>>(wq, wqb, nw4);
  cvt_bf16<<<(nw4+255)/256, 256, 0, stream>>>(wk, wkb, nw4);
  cvt_bf16<<<(nw4+255)/256, 256, 0, stream>>>(wv, wvb, nw4);
  cvt_bf16<<<(nw4+255)/256, 256, 0, stream>>>(wo, wob, nw4);

  gemm_bt<0><<<dim3(18, 32), 256, 0, stream>>>(xb, wqb, wkb, wvb, bq, bk, bv,
                                               qb, kb, vtb, nullptr);
  attn_fwd<<<dim3(32, 24), 256, 0, stream>>>(qb, kb, vtb, attb);
  gemm_bt<1><<<dim3(6, 32), 256, 0, stream>>>(attb, wob, nullptr, nullptr, bo, nullptr, nullptr,
                                              nullptr, nullptr, nullptr, out);
}

// Round 3
// 130.875 us; speedup vs baseline: 1.8818x; 1.1501x over previous
//
#include <hip/hip_runtime.h>

// MHA forward, MI355X gfx950. bf16 MFMA pipeline, fp32 accumulate.
// Stages: cvt(fp32->bf16) -> fused QKV gemm_bt (epilogue: Q*scale, K, V^T)
//         -> flash attention v3 (2-wave blocks, balanced tile pairing,
//            defer-max, deferred l-sum) -> out-proj gemm_bt.

#define DM   768
#define SEQ  2048
#define NB   2
#define NH   12
#define DK   64
#define MROWS (NB*SEQ)                       // 4096
#define QSCALE 0.18033688011112042f          // (1/sqrt(64)) * log2(e): softmax in exp2 domain

typedef unsigned short u16;
typedef __bf16 bf16x8 __attribute__((ext_vector_type(8)));
typedef float  f32x4  __attribute__((ext_vector_type(4)));
typedef unsigned int u32x4 __attribute__((ext_vector_type(4)));

__device__ __forceinline__ u16 f2bf(float f) {      // RNE f32 -> bf16
  unsigned u = __builtin_bit_cast(unsigned, f);
  u += 0x7fffu + ((u >> 16) & 1u);
  return (u16)(u >> 16);
}

__device__ __forceinline__ bf16x8 ldbf8(const u16* p) {   // 16B aligned load
  return __builtin_bit_cast(bf16x8, *(const u32x4*)p);
}

__device__ __forceinline__ void gl_lds16(const void* g, void* l) {
  __builtin_amdgcn_global_load_lds((__attribute__((address_space(1))) void*)g,
                                   (__attribute__((address_space(3))) void*)l,
                                   16, 0, 0);
}

// ---------------- fp32 -> bf16 converts ----------------
__global__ void cvt_bf16(const float* __restrict__ s, u16* __restrict__ d, int n4) {
  int i = blockIdx.x * blockDim.x + threadIdx.x;
  if (i < n4) {
    const float4 v = ((const float4*)s)[i];
    ushort4 r;
    r.x = f2bf(v.x); r.y = f2bf(v.y); r.z = f2bf(v.z); r.w = f2bf(v.w);
    ((ushort4*)d)[i] = r;
  }
}

// 4 weight matrices, contiguous destination
__global__ void cvt_w4(const float* __restrict__ s0, const float* __restrict__ s1,
                       const float* __restrict__ s2, const float* __restrict__ s3,
                       u16* __restrict__ d, int n4) {
  const int i = blockIdx.x * blockDim.x + threadIdx.x;
  const int m = i / n4, r = i - m * n4;
  const float* s = (m == 0) ? s0 : (m == 1) ? s1 : (m == 2) ? s2 : s3;
  const float4 v = ((const float4*)s)[r];
  ushort4 rr;
  rr.x = f2bf(v.x); rr.y = f2bf(v.y); rr.z = f2bf(v.z); rr.w = f2bf(v.w);
  ((ushort4*)d)[i] = rr;
}

// ---------------- gemm_bt: C[m][n] = sum_k A[m][k]*B[n][k]  (m97 structure) ----
template <int EPI>
__global__ __launch_bounds__(256) void gemm_bt(
    const u16* __restrict__ A,
    const u16* __restrict__ B0, const u16* __restrict__ B1, const u16* __restrict__ B2,
    const float* __restrict__ bias0, const float* __restrict__ bias1, const float* __restrict__ bias2,
    u16* __restrict__ q_out, u16* __restrict__ k_out, u16* __restrict__ vt_out,
    float* __restrict__ f_out)
{
  __shared__ u16 At[128*32];
  __shared__ u16 Bt[128*32];
  const int tid = threadIdx.x;
  const int w = tid >> 6, lane = tid & 63;
  const int lg = lane >> 4, ll = lane & 15;
  const int bn = blockIdx.x, bm = blockIdx.y;
  const int row0 = bm * 128;

  const u16* Bm; const float* bias; int col0; int mat = 0;
  if (EPI == 0) {
    mat  = bn / 6;                               // 0=Q 1=K 2=V
    Bm   = (mat == 0) ? B0 : (mat == 1) ? B1 : B2;
    bias = (mat == 0) ? bias0 : (mat == 1) ? bias1 : bias2;
    col0 = (bn % 6) * 128;
  } else {
    Bm = B0; bias = bias0; col0 = bn * 128;
  }
  const int wr = w >> 1, wc = w & 1;

  f32x4 acc[4][4] = {};
  const int c0 = w, c1 = w + 4;
  const int ofs0 = c0*1024 + lane*16;
  const int ofs1 = c1*1024 + lane*16;

  for (int k0 = 0; k0 < DM; k0 += 32) {
    __syncthreads();
    gl_lds16((const char*)A  + ((size_t)(row0 + (ofs0>>6))*DM + k0)*2 + (ofs0&63), (char*)At + c0*1024);
    gl_lds16((const char*)A  + ((size_t)(row0 + (ofs1>>6))*DM + k0)*2 + (ofs1&63), (char*)At + c1*1024);
    gl_lds16((const char*)Bm + ((size_t)(col0 + (ofs0>>6))*DM + k0)*2 + (ofs0&63), (char*)Bt + c0*1024);
    gl_lds16((const char*)Bm + ((size_t)(col0 + (ofs1>>6))*DM + k0)*2 + (ofs1&63), (char*)Bt + c1*1024);
    __syncthreads();

    bf16x8 fa[4], fb[4];
#pragma unroll
    for (int m = 0; m < 4; ++m)
      fa[m] = ldbf8(&At[(wr*64 + m*16 + ll)*32 + lg*8]);
#pragma unroll
    for (int n = 0; n < 4; ++n)
      fb[n] = ldbf8(&Bt[(wc*64 + n*16 + ll)*32 + lg*8]);
#pragma unroll
    for (int m = 0; m < 4; ++m)
#pragma unroll
      for (int n = 0; n < 4; ++n)
        acc[m][n] = __builtin_amdgcn_mfma_f32_16x16x32_bf16(fa[m], fb[n], acc[m][n], 0, 0, 0);
  }

#pragma unroll
  for (int m = 0; m < 4; ++m) {
#pragma unroll
    for (int n = 0; n < 4; ++n) {
      const int gn  = col0 + wc*64 + n*16 + ll;
      const float bv = bias[gn];
      const int gm0 = row0 + wr*64 + m*16 + lg*4;
#pragma unroll
      for (int j = 0; j < 4; ++j) {
        const float v = acc[m][n][j] + bv;
        const int gm = gm0 + j;
        if (EPI == 0) {
          const int b = gm >> 11, s = gm & 2047;
          const int h = gn >> 6,  d = gn & 63;
          const size_t bh = (size_t)(b*NH + h);
          if (mat == 0)      q_out[(bh*SEQ + s)*DK + d] = f2bf(v * QSCALE);
          else if (mat == 1) k_out[(bh*SEQ + s)*DK + d] = f2bf(v);
          else               vt_out[(bh*DK + d)*SEQ + s] = f2bf(v);
        } else {
          f_out[(size_t)gm*DM + gn] = v;
        }
      }
    }
  }
}

// ---------------- flash attention v3 ----------------
// grid (32, 24): y = (b*NH+h); block = 128 threads (2 waves).
// Block x=b processes q-tiles {63-b, b} (32 rows each) SEQUENTIALLY -> every
// block does exactly 33 KV-tile iterations (perfect balance, 3 blocks/CU flat).
// Per tile: wave w owns 16 q-rows. Swapped QK^T (S^T = mfma(K,Q)): lane (ll,lg)
// holds S[q0+ll][kt*16+lg*4+j]. Defer-max (T13): skip cross-lane max + rescale
// unless local max exceeds running max by >8 (exp2 domain). l-sum kept as
// per-lane partials, reduced across lane-groups once after the loop.

__device__ __forceinline__ void stage_kv(const u16* kp, const u16* vp, int kv0,
                                         u16* Kb, u16* Vb, int w, int lane) {
  const char* kg = (const char*)kp + (size_t)kv0 * 128;   // K rows contiguous (128B/row)
  const char* vg = (const char*)vp + (size_t)kv0 * 2;     // V^T rows stride 4096B
#pragma unroll
  for (int r = 0; r < 4; ++r) {
    const int base = (w*4 + r) * 1024;          // wave-uniform LDS base; HW adds lane*16
    const int a = base + lane*16;
    const int row = a >> 7;                     // 128B rows
    const int cs  = ((a >> 4) & 7) ^ (row & 7); // inverse-swizzled source chunk
    gl_lds16(kg + row*128 + cs*16, (char*)Kb + base);
    gl_lds16(vg + (size_t)row*4096 + cs*16, (char*)Vb + base);
  }
}

__device__ __forceinline__ bf16x8 ldtile(const u16* T, int row, int wo) {
  // swizzled read of 16B at logical (row, byte-offset wo) from a [64][64] bf16 tile
  return ldbf8((const u16*)((const char*)T + row*128 + (wo ^ ((row & 7) << 4))));
}

__global__ __launch_bounds__(128) void attn_fwd(
    const u16* __restrict__ qb, const u16* __restrict__ kb,
    const u16* __restrict__ vtb, u16* __restrict__ attb)
{
  __shared__ u16 Kt[2][64*64];                  // 8KB per buffer
  __shared__ u16 Vt[2][64*64];
  __shared__ u16 Pw[2][16*72];                  // per-wave P repack, pad 64->72
  const int bh = blockIdx.y;
  const int tid = threadIdx.x;
  const int w = tid >> 6, lane = tid & 63;
  const int lg = lane >> 4, ll = lane & 15;
  const u16* qp = qb  + (size_t)bh * SEQ * DK;
  const u16* kp = kb  + (size_t)bh * SEQ * DK;
  const u16* vp = vtb + (size_t)bh * DK * SEQ;
  const int b = bh / NH, hh = bh % NH;
  u16* Pl = &Pw[w][0];

#pragma unroll 1
  for (int half = 0; half < 2; ++half) {
    const int tile = half ? (int)blockIdx.x : 63 - (int)blockIdx.x;
    const int nt = (tile >> 1) + 1;              // KV tiles needed (causal)
    const int q0 = tile * 32 + w * 16;

    const bf16x8 qf0 = ldbf8(&qp[(size_t)(q0 + ll)*DK + lg*8]);
    const bf16x8 qf1 = ldbf8(&qp[(size_t)(q0 + ll)*DK + 32 + lg*8]);

    f32x4 o[4] = {};                             // lane holds O[q0+ll][dt*16+lg*4+j]
    float mrun = -1e30f, lrun = 0.f;             // per-lane; lrun = partial over own k-chunks

    stage_kv(kp, vp, 0, Kt[0], Vt[0], w, lane);
    __syncthreads();

    for (int t = 0; t < nt; ++t) {
      const int cur = t & 1;
      if (t + 1 < nt) stage_kv(kp, vp, (t+1)*64, Kt[cur^1], Vt[cur^1], w, lane);
      const u16* Kc = Kt[cur];
      const u16* Vc = Vt[cur];

      // S^T = K . Q^T over d=64
      f32x4 st[4] = {};
#pragma unroll
      for (int kt = 0; kt < 4; ++kt) {
        const int r = kt*16 + ll;
        st[kt] = __builtin_amdgcn_mfma_f32_16x16x32_bf16(ldtile(Kc, r, lg*16),      qf0, st[kt], 0,0,0);
        st[kt] = __builtin_amdgcn_mfma_f32_16x16x32_bf16(ldtile(Kc, r, 64 + lg*16), qf1, st[kt], 0,0,0);
      }
      if (t == nt - 1) {                         // diagonal tile: causal mask
        const int kvb = t*64;
#pragma unroll
        for (int kt = 0; kt < 4; ++kt)
#pragma unroll
          for (int j = 0; j < 4; ++j)
            if (kvb + kt*16 + lg*4 + j > q0 + ll) st[kt][j] = -1e30f;
      }

      // local (per-lane) max over this lane's 16 scores
      float lm = -1e30f;
#pragma unroll
      for (int kt = 0; kt < 4; ++kt)
        lm = fmaxf(lm, fmaxf(fmaxf(st[kt][0], st[kt][1]), fmaxf(st[kt][2], st[kt][3])));

      if (!__all(lm <= mrun + 8.f)) {            // rare: real max growth -> rescale
        float mt = lm;
        mt = fmaxf(mt, __shfl_xor(mt, 16));
        mt = fmaxf(mt, __shfl_xor(mt, 32));
        const float mn = fmaxf(mrun, mt);
        const float sc = exp2f(mrun - mn);
        lrun *= sc;
#pragma unroll
        for (int dt = 0; dt < 4; ++dt)
#pragma unroll
          for (int j = 0; j < 4; ++j)
            o[dt][j] *= sc;
        mrun = mn;
      }

      float psum = 0.f;
      unsigned pd[8];
#pragma unroll
      for (int kt = 0; kt < 4; ++kt) {
        const float e0 = exp2f(st[kt][0] - mrun);
        const float e1 = exp2f(st[kt][1] - mrun);
        const float e2 = exp2f(st[kt][2] - mrun);
        const float e3 = exp2f(st[kt][3] - mrun);
        psum += (e0 + e1) + (e2 + e3);
        pd[kt*2]   = (unsigned)f2bf(e0) | ((unsigned)f2bf(e1) << 16);
        pd[kt*2+1] = (unsigned)f2bf(e2) | ((unsigned)f2bf(e3) << 16);
      }
      lrun += psum;                              // per-lane partial (own k-chunks only)

      // P repack (same-wave LDS round-trip; DS in-order within wave)
#pragma unroll
      for (int kt = 0; kt < 4; ++kt)
        *(uint2*)&Pl[ll*72 + kt*16 + lg*4] = make_uint2(pd[kt*2], pd[kt*2+1]);
      const bf16x8 pb0 = ldbf8(&Pl[ll*72 + lg*8]);       // P[q=ll][lg*8..+7]
      const bf16x8 pb1 = ldbf8(&Pl[ll*72 + 32 + lg*8]);

      // O^T += V^T . P^T
#pragma unroll
      for (int dt = 0; dt < 4; ++dt) {
        const int r = dt*16 + ll;
        o[dt] = __builtin_amdgcn_mfma_f32_16x16x32_bf16(ldtile(Vc, r, lg*16),      pb0, o[dt], 0,0,0);
        o[dt] = __builtin_amdgcn_mfma_f32_16x16x32_bf16(ldtile(Vc, r, 64 + lg*16), pb1, o[dt], 0,0,0);
      }
      __syncthreads();   // stage(t+1) landed (vmcnt drained) + buf[cur] reads done
    }

    // epilogue: reduce l across the 4 lane-groups of each q-row, store
    float lt = lrun;
    lt += __shfl_xor(lt, 16);
    lt += __shfl_xor(lt, 32);
    const float rl = 1.0f / lt;
    u16* orow = &attb[(size_t)(b*SEQ + q0 + ll)*DM + hh*64];
#pragma unroll
    for (int dt = 0; dt < 4; ++dt) {
      ushort4 rr;
      rr.x = f2bf(o[dt][0] * rl);
      rr.y = f2bf(o[dt][1] * rl);
      rr.z = f2bf(o[dt][2] * rl);
      rr.w = f2bf(o[dt][3] * rl);
      *(ushort4*)&orow[dt*16 + lg*4] = rr;
    }
  }
}

// ---------------- launch ----------------
extern "C" void kernel_launch(void* const* d_in, const int* in_sizes, int n_in,
                              void* d_out, int out_size, void* d_ws, size_t ws_size,
                              hipStream_t stream) {
  const float* x  = (const float*)d_in[0];
  const float* wq = (const float*)d_in[1];
  const float* bq = (const float*)d_in[2];
  const float* wk = (const float*)d_in[3];
  const float* bk = (const float*)d_in[4];
  const float* wv = (const float*)d_in[5];
  const float* bv = (const float*)d_in[6];
  const float* wo = (const float*)d_in[7];
  const float* bo = (const float*)d_in[8];
  float* out = (float*)d_out;

  char* ws = (char*)d_ws;
  u16* xb   = (u16*)(ws);               // [4096][768]
  u16* wqb  = (u16*)(ws + 6291456);     // [768][768] x4 contiguous (wq,wk,wv,wo)
  u16* wkb  = (u16*)(ws + 7471104);
  u16* wvb  = (u16*)(ws + 8650752);
  u16* wob  = (u16*)(ws + 9830400);
  u16* qb   = (u16*)(ws + 11010048);    // [24][2048][64] scaled
  u16* kb   = (u16*)(ws + 17301504);    // [24][2048][64]
  u16* vtb  = (u16*)(ws + 23592960);    // [24][64][2048]
  u16* attb = (u16*)(ws + 29884416);    // [4096][768]

  const int nx4 = MROWS*DM/4;           // 786432
  const int nw4 = DM*DM/4;              // 147456
  cvt_bf16<<<(nx4+255)/256, 256, 0, stream>>>(x, xb, nx4);
  cvt_w4<<<(4*nw4)/256, 256, 0, stream>>>(wq, wk, wv, wo, wqb, nw4);

  gemm_bt<0><<<dim3(18, 32), 256, 0, stream>>>(xb, wqb, wkb, wvb, bq, bk, bv,
                                               qb, kb, vtb, nullptr);
  attn_fwd<<<dim3(32, 24), 128, 0, stream>>>(qb, kb, vtb, attb);
  gemm_bt<1><<<dim3(6, 32), 256, 0, stream>>>(attb, wob, nullptr, nullptr, bo, nullptr, nullptr,
                                              nullptr, nullptr, nullptr, out);
}

// Round 4
// 126.248 us; speedup vs baseline: 1.9507x; 1.0367x over previous
//
#include <hip/hip_runtime.h>

// MHA forward, MI355X gfx950. bf16 MFMA pipeline, fp32 accumulate.
// Stages: cvt(fp32->bf16) -> fused QKV gemm_bt (epilogue: Q*scale, K, V^T)
//         -> flash attention v4 (balanced pairs + XCD-clustered mapping)
//         -> out-proj gemm_bt.

#define DM   768
#define SEQ  2048
#define NB   2
#define NH   12
#define DK   64
#define MROWS (NB*SEQ)                       // 4096
#define QSCALE 0.18033688011112042f          // (1/sqrt(64)) * log2(e): softmax in exp2 domain

typedef unsigned short u16;
typedef __bf16 bf16x8 __attribute__((ext_vector_type(8)));
typedef float  f32x4  __attribute__((ext_vector_type(4)));
typedef unsigned int u32x4 __attribute__((ext_vector_type(4)));

__device__ __forceinline__ u16 f2bf(float f) {      // RNE f32 -> bf16
  unsigned u = __builtin_bit_cast(unsigned, f);
  u += 0x7fffu + ((u >> 16) & 1u);
  return (u16)(u >> 16);
}

__device__ __forceinline__ bf16x8 ldbf8(const u16* p) {   // 16B aligned load
  return __builtin_bit_cast(bf16x8, *(const u32x4*)p);
}

__device__ __forceinline__ void gl_lds16(const void* g, void* l) {
  __builtin_amdgcn_global_load_lds((__attribute__((address_space(1))) void*)g,
                                   (__attribute__((address_space(3))) void*)l,
                                   16, 0, 0);
}

// ---------------- fp32 -> bf16 converts ----------------
__global__ void cvt_bf16(const float* __restrict__ s, u16* __restrict__ d, int n4) {
  int i = blockIdx.x * blockDim.x + threadIdx.x;
  if (i < n4) {
    const float4 v = ((const float4*)s)[i];
    ushort4 r;
    r.x = f2bf(v.x); r.y = f2bf(v.y); r.z = f2bf(v.z); r.w = f2bf(v.w);
    ((ushort4*)d)[i] = r;
  }
}

// 4 weight matrices, contiguous destination
__global__ void cvt_w4(const float* __restrict__ s0, const float* __restrict__ s1,
                       const float* __restrict__ s2, const float* __restrict__ s3,
                       u16* __restrict__ d, int n4) {
  const int i = blockIdx.x * blockDim.x + threadIdx.x;
  const int m = i / n4, r = i - m * n4;
  const float* s = (m == 0) ? s0 : (m == 1) ? s1 : (m == 2) ? s2 : s3;
  const float4 v = ((const float4*)s)[r];
  ushort4 rr;
  rr.x = f2bf(v.x); rr.y = f2bf(v.y); rr.z = f2bf(v.z); rr.w = f2bf(v.w);
  ((ushort4*)d)[i] = rr;
}

// ---------------- gemm_bt: C[m][n] = sum_k A[m][k]*B[n][k]  (m97 structure) ----
template <int EPI>
__global__ __launch_bounds__(256) void gemm_bt(
    const u16* __restrict__ A,
    const u16* __restrict__ B0, const u16* __restrict__ B1, const u16* __restrict__ B2,
    const float* __restrict__ bias0, const float* __restrict__ bias1, const float* __restrict__ bias2,
    u16* __restrict__ q_out, u16* __restrict__ k_out, u16* __restrict__ vt_out,
    float* __restrict__ f_out)
{
  __shared__ u16 At[128*32];
  __shared__ u16 Bt[128*32];
  const int tid = threadIdx.x;
  const int w = tid >> 6, lane = tid & 63;
  const int lg = lane >> 4, ll = lane & 15;
  const int bn = blockIdx.x, bm = blockIdx.y;
  const int row0 = bm * 128;

  const u16* Bm; const float* bias; int col0; int mat = 0;
  if (EPI == 0) {
    mat  = bn / 6;                               // 0=Q 1=K 2=V
    Bm   = (mat == 0) ? B0 : (mat == 1) ? B1 : B2;
    bias = (mat == 0) ? bias0 : (mat == 1) ? bias1 : bias2;
    col0 = (bn % 6) * 128;
  } else {
    Bm = B0; bias = bias0; col0 = bn * 128;
  }
  const int wr = w >> 1, wc = w & 1;

  f32x4 acc[4][4] = {};
  const int c0 = w, c1 = w + 4;
  const int ofs0 = c0*1024 + lane*16;
  const int ofs1 = c1*1024 + lane*16;

  for (int k0 = 0; k0 < DM; k0 += 32) {
    __syncthreads();
    gl_lds16((const char*)A  + ((size_t)(row0 + (ofs0>>6))*DM + k0)*2 + (ofs0&63), (char*)At + c0*1024);
    gl_lds16((const char*)A  + ((size_t)(row0 + (ofs1>>6))*DM + k0)*2 + (ofs1&63), (char*)At + c1*1024);
    gl_lds16((const char*)Bm + ((size_t)(col0 + (ofs0>>6))*DM + k0)*2 + (ofs0&63), (char*)Bt + c0*1024);
    gl_lds16((const char*)Bm + ((size_t)(col0 + (ofs1>>6))*DM + k0)*2 + (ofs1&63), (char*)Bt + c1*1024);
    __syncthreads();

    bf16x8 fa[4], fb[4];
#pragma unroll
    for (int m = 0; m < 4; ++m)
      fa[m] = ldbf8(&At[(wr*64 + m*16 + ll)*32 + lg*8]);
#pragma unroll
    for (int n = 0; n < 4; ++n)
      fb[n] = ldbf8(&Bt[(wc*64 + n*16 + ll)*32 + lg*8]);
#pragma unroll
    for (int m = 0; m < 4; ++m)
#pragma unroll
      for (int n = 0; n < 4; ++n)
        acc[m][n] = __builtin_amdgcn_mfma_f32_16x16x32_bf16(fa[m], fb[n], acc[m][n], 0, 0, 0);
  }

#pragma unroll
  for (int m = 0; m < 4; ++m) {
#pragma unroll
    for (int n = 0; n < 4; ++n) {
      const int gn  = col0 + wc*64 + n*16 + ll;
      const float bv = bias[gn];
      const int gm0 = row0 + wr*64 + m*16 + lg*4;
#pragma unroll
      for (int j = 0; j < 4; ++j) {
        const float v = acc[m][n][j] + bv;
        const int gm = gm0 + j;
        if (EPI == 0) {
          const int b = gm >> 11, s = gm & 2047;
          const int h = gn >> 6,  d = gn & 63;
          const size_t bh = (size_t)(b*NH + h);
          if (mat == 0)      q_out[(bh*SEQ + s)*DK + d] = f2bf(v * QSCALE);
          else if (mat == 1) k_out[(bh*SEQ + s)*DK + d] = f2bf(v);
          else               vt_out[(bh*DK + d)*SEQ + s] = f2bf(v);
        } else {
          f_out[(size_t)gm*DM + gn] = v;
        }
      }
    }
  }
}

// ---------------- flash attention v4 ----------------
// grid 768 linear, XCD-clustered: xcd = L&7 (dispatch round-robins XCDs on
// linear id), bh = xcd*3 + (L>>3)%3, pair = (L>>3)/3. Each XCD owns 3 bh ->
// per-XCD L2 working set (K+V+Q ~ 2.3MB) fits the 4MB L2: KV staging becomes
// L2-hit and the 1-deep prefetch fully hides it.
// Block = 128 thr (2 waves); processes q-tiles {63-pair, pair} (32 rows each)
// sequentially -> every block exactly 33 KV-tile iterations.
// Swapped QK^T (S^T = mfma(K,Q)); defer-max (T13, thr=8); per-lane partial
// l-sum reduced once at the end.

__device__ __forceinline__ void stage_kv(const u16* kp, const u16* vp, int kv0,
                                         u16* Kb, u16* Vb, int w, int lane) {
  const char* kg = (const char*)kp + (size_t)kv0 * 128;   // K rows contiguous (128B/row)
  const char* vg = (const char*)vp + (size_t)kv0 * 2;     // V^T rows stride 4096B
#pragma unroll
  for (int r = 0; r < 4; ++r) {
    const int base = (w*4 + r) * 1024;          // wave-uniform LDS base; HW adds lane*16
    const int a = base + lane*16;
    const int row = a >> 7;                     // 128B rows
    const int cs  = ((a >> 4) & 7) ^ (row & 7); // inverse-swizzled source chunk
    gl_lds16(kg + row*128 + cs*16, (char*)Kb + base);
    gl_lds16(vg + (size_t)row*4096 + cs*16, (char*)Vb + base);
  }
}

__device__ __forceinline__ bf16x8 ldtile(const u16* T, int row, int wo) {
  // swizzled read of 16B at logical (row, byte-offset wo) from a [64][64] bf16 tile
  return ldbf8((const u16*)((const char*)T + row*128 + (wo ^ ((row & 7) << 4))));
}

__global__ __launch_bounds__(128) void attn_fwd(
    const u16* __restrict__ qb, const u16* __restrict__ kb,
    const u16* __restrict__ vtb, u16* __restrict__ attb)
{
  __shared__ u16 Kt[2][64*64];                  // 8KB per buffer
  __shared__ u16 Vt[2][64*64];
  __shared__ u16 Pw[2][16*72];                  // per-wave P repack, pad 64->72
  const int L = blockIdx.x;
  const int xcd = L & 7, rr0 = L >> 3;
  const int bh = xcd * 3 + (rr0 % 3);            // XCD-clustered: 3 bh per XCD
  const int pair = rr0 / 3;                      // 0..31
  const int tid = threadIdx.x;
  const int w = tid >> 6, lane = tid & 63;
  const int lg = lane >> 4, ll = lane & 15;
  const u16* qp = qb  + (size_t)bh * SEQ * DK;
  const u16* kp = kb  + (size_t)bh * SEQ * DK;
  const u16* vp = vtb + (size_t)bh * DK * SEQ;
  const int b = bh / NH, hh = bh % NH;
  u16* Pl = &Pw[w][0];

#pragma unroll 1
  for (int half = 0; half < 2; ++half) {
    const int tile = half ? pair : 63 - pair;
    const int nt = (tile >> 1) + 1;              // KV tiles needed (causal)
    const int q0 = tile * 32 + w * 16;

    const bf16x8 qf0 = ldbf8(&qp[(size_t)(q0 + ll)*DK + lg*8]);
    const bf16x8 qf1 = ldbf8(&qp[(size_t)(q0 + ll)*DK + 32 + lg*8]);

    f32x4 o[4] = {};                             // lane holds O[q0+ll][dt*16+lg*4+j]
    float mrun = 0.f, lrun = 0.f;                // m=0 valid: defer-thr bounds P<=2^8

    stage_kv(kp, vp, 0, Kt[0], Vt[0], w, lane);
    __syncthreads();

    for (int t = 0; t < nt; ++t) {
      const int cur = t & 1;
      if (t + 1 < nt) stage_kv(kp, vp, (t+1)*64, Kt[cur^1], Vt[cur^1], w, lane);
      const u16* Kc = Kt[cur];
      const u16* Vc = Vt[cur];

      // S^T = K . Q^T over d=64
      f32x4 st[4] = {};
#pragma unroll
      for (int kt = 0; kt < 4; ++kt) {
        const int r = kt*16 + ll;
        st[kt] = __builtin_amdgcn_mfma_f32_16x16x32_bf16(ldtile(Kc, r, lg*16),      qf0, st[kt], 0,0,0);
        st[kt] = __builtin_amdgcn_mfma_f32_16x16x32_bf16(ldtile(Kc, r, 64 + lg*16), qf1, st[kt], 0,0,0);
      }
      if (t == nt - 1) {                         // diagonal tile: causal mask
        const int kvb = t*64;
#pragma unroll
        for (int kt = 0; kt < 4; ++kt)
#pragma unroll
          for (int j = 0; j < 4; ++j)
            if (kvb + kt*16 + lg*4 + j > q0 + ll) st[kt][j] = -1e30f;
      }

      // local (per-lane) max over this lane's 16 scores
      float lm = -1e30f;
#pragma unroll
      for (int kt = 0; kt < 4; ++kt)
        lm = fmaxf(lm, fmaxf(fmaxf(st[kt][0], st[kt][1]), fmaxf(st[kt][2], st[kt][3])));

      if (!__all(lm <= mrun + 8.f)) {            // rare: real max growth -> rescale
        float mt = lm;
        mt = fmaxf(mt, __shfl_xor(mt, 16));
        mt = fmaxf(mt, __shfl_xor(mt, 32));
        const float mn = fmaxf(mrun, mt);
        const float sc = exp2f(mrun - mn);
        lrun *= sc;
#pragma unroll
        for (int dt = 0; dt < 4; ++dt)
#pragma unroll
          for (int j = 0; j < 4; ++j)
            o[dt][j] *= sc;
        mrun = mn;
      }

      float psum = 0.f;
      unsigned pd[8];
#pragma unroll
      for (int kt = 0; kt < 4; ++kt) {
        const float e0 = exp2f(st[kt][0] - mrun);
        const float e1 = exp2f(st[kt][1] - mrun);
        const float e2 = exp2f(st[kt][2] - mrun);
        const float e3 = exp2f(st[kt][3] - mrun);
        psum += (e0 + e1) + (e2 + e3);
        pd[kt*2]   = (unsigned)f2bf(e0) | ((unsigned)f2bf(e1) << 16);
        pd[kt*2+1] = (unsigned)f2bf(e2) | ((unsigned)f2bf(e3) << 16);
      }
      lrun += psum;                              // per-lane partial (own k-chunks only)

      // P repack (same-wave LDS round-trip; DS in-order within wave)
#pragma unroll
      for (int kt = 0; kt < 4; ++kt)
        *(uint2*)&Pl[ll*72 + kt*16 + lg*4] = make_uint2(pd[kt*2], pd[kt*2+1]);
      const bf16x8 pb0 = ldbf8(&Pl[ll*72 + lg*8]);       // P[q=ll][lg*8..+7]
      const bf16x8 pb1 = ldbf8(&Pl[ll*72 + 32 + lg*8]);

      // O^T += V^T . P^T
#pragma unroll
      for (int dt = 0; dt < 4; ++dt) {
        const int r = dt*16 + ll;
        o[dt] = __builtin_amdgcn_mfma_f32_16x16x32_bf16(ldtile(Vc, r, lg*16),      pb0, o[dt], 0,0,0);
        o[dt] = __builtin_amdgcn_mfma_f32_16x16x32_bf16(ldtile(Vc, r, 64 + lg*16), pb1, o[dt], 0,0,0);
      }
      __syncthreads();   // stage(t+1) landed (vmcnt drained) + buf[cur] reads done
    }

    // epilogue: reduce l across the 4 lane-groups of each q-row, store
    float lt = lrun;
    lt += __shfl_xor(lt, 16);
    lt += __shfl_xor(lt, 32);
    const float rl = 1.0f / lt;
    u16* orow = &attb[(size_t)(b*SEQ + q0 + ll)*DM + hh*64];
#pragma unroll
    for (int dt = 0; dt < 4; ++dt) {
      ushort4 rw;
      rw.x = f2bf(o[dt][0] * rl);
      rw.y = f2bf(o[dt][1] * rl);
      rw.z = f2bf(o[dt][2] * rl);
      rw.w = f2bf(o[dt][3] * rl);
      *(ushort4*)&orow[dt*16 + lg*4] = rw;
    }
  }
}

// ---------------- launch ----------------
extern "C" void kernel_launch(void* const* d_in, const int* in_sizes, int n_in,
                              void* d_out, int out_size, void* d_ws, size_t ws_size,
                              hipStream_t stream) {
  const float* x  = (const float*)d_in[0];
  const float* wq = (const float*)d_in[1];
  const float* bq = (const float*)d_in[2];
  const float* wk = (const float*)d_in[3];
  const float* bk = (const float*)d_in[4];
  const float* wv = (const float*)d_in[5];
  const float* bv = (const float*)d_in[6];
  const float* wo = (const float*)d_in[7];
  const float* bo = (const float*)d_in[8];
  float* out = (float*)d_out;

  char* ws = (char*)d_ws;
  u16* xb   = (u16*)(ws);               // [4096][768]
  u16* wqb  = (u16*)(ws + 6291456);     // [768][768] x4 contiguous (wq,wk,wv,wo)
  u16* wkb  = (u16*)(ws + 7471104);
  u16* wvb  = (u16*)(ws + 8650752);
  u16* wob  = (u16*)(ws + 9830400);
  u16* qb   = (u16*)(ws + 11010048);    // [24][2048][64] scaled
  u16* kb   = (u16*)(ws + 17301504);    // [24][2048][64]
  u16* vtb  = (u16*)(ws + 23592960);    // [24][64][2048]
  u16* attb = (u16*)(ws + 29884416);    // [4096][768]

  const int nx4 = MROWS*DM/4;           // 786432
  const int nw4 = DM*DM/4;              // 147456
  cvt_bf16<<<(nx4+255)/256, 256, 0, stream>>>(x, xb, nx4);
  cvt_w4<<<(4*nw4)/256, 256, 0, stream>>>(wq, wk, wv, wo, wqb, nw4);

  gemm_bt<0><<<dim3(18, 32), 256, 0, stream>>>(xb, wqb, wkb, wvb, bq, bk, bv,
                                               qb, kb, vtb, nullptr);
  attn_fwd<<<768, 128, 0, stream>>>(qb, kb, vtb, attb);
  gemm_bt<1><<<dim3(6, 32), 256, 0, stream>>>(attb, wob, nullptr, nullptr, bo, nullptr, nullptr,
                                              nullptr, nullptr, nullptr, out);
}